// Round 3
// baseline (1454.451 us; speedup 1.0000x reference)
//
#include <hip/hip_runtime.h>
#include <stdint.h>

// PyramidGrid (instant-NGP hash grid, simplex/tetrahedral interp) forward.
// BATCH = 2^21 points, 16 levels, LEVEL_DIM=2, table rows = 7,114,752.
// All per-level hash sizes are powers of two -> modulo == AND mask.
//
// R2: non-temporal stores for the 268MB output stream + NT loads for the 24MB
// input stream (R1 intent; fixed compile error — builtin needs a clang
// ext_vector_type, not HIP's float4 class). Theory: the write stream thrashes
// the 256MB memory-side Infinity Cache, evicting the 57MB hash table and
// forcing 4.76GB of HBM re-fetch per dispatch. NT traffic leaves L3 to the table.

constexpr uint32_t kBatch = 1u << 21;

typedef float f32x4 __attribute__((ext_vector_type(4)));

__global__ __launch_bounds__(256) void pyramid_fwd(
    const float* __restrict__ in,    // [B,3]
    const float* __restrict__ emb,   // [7114752,2]
    float* __restrict__ out)         // [B,32]
{
    const uint32_t b = blockIdx.x * 256u + threadIdx.x;

    const float x0 = __builtin_nontemporal_load(in + 3u * b + 0u);
    const float x1 = __builtin_nontemporal_load(in + 3u * b + 1u);
    const float x2 = __builtin_nontemporal_load(in + 3u * b + 2u);

    float acc[32];

    // cumulative row offsets (prev) and hash masks per level
    constexpr uint32_t PREV[16] = {
        0u, 4096u, 36864u, 299008u, 823296u, 1347584u, 1871872u, 2396160u,
        2920448u, 3444736u, 3969024u, 4493312u, 5017600u, 5541888u, 6066176u, 6590464u};
    constexpr uint32_t MASK[16] = {
        4095u, 32767u, 262143u, 524287u, 524287u, 524287u, 524287u, 524287u,
        524287u, 524287u, 524287u, 524287u, 524287u, 524287u, 524287u, 524287u};

#pragma unroll
    for (int lvl = 0; lvl < 16; ++lvl) {
        const float res = (float)(16 << lvl);
        const uint32_t mask = MASK[lvl];
        const uint32_t prev = PREV[lvl];

        const float fx0 = x0 * res;
        const float fx1 = x1 * res;
        const float fx2 = x2 * res;
        const int i0 = (int)fx0;            // trunc == floor (x >= 0), matches astype(int32)
        const int i1 = (int)fx1;
        const int i2 = (int)fx2;
        const float f0 = fx0 - (float)i0;   // exact fp32, matches reference
        const float f1 = fx1 - (float)i1;
        const float f2 = fx2 - (float)i2;

        // stable ascending ranks (== inv_inds of jnp.argsort, stable)
        const int r0 = (int)(f1 < f0) + (int)(f2 < f0);
        const int r1 = (int)(f0 < f1) + (int)(f2 < f1) + (int)(f0 == f1);
        const int r2 = (int)(f0 < f2) + (int)(f1 < f2) + (int)(f0 == f2) + (int)(f1 == f2);

        // sorted frac values (exact selections)
        const float s0 = fminf(fminf(f0, f1), f2);
        const float s2 = fmaxf(fmaxf(f0, f1), f2);
        const float s1 = __builtin_amdgcn_fmed3f(f0, f1, f2);

        const float w0 = s0;          // weight of corner with all +1
        const float w1 = s1 - s0;
        const float w2 = s2 - s1;
        const float w3 = 1.0f - s2;   // weight of base corner

        // hash components (uint32 wrap-around multiply, PRIMES = {1, 2654435761, 805459861})
        const uint32_t A0 = (uint32_t)i0;
        const uint32_t A1 = A0 + 1u;
        const uint32_t B0 = (uint32_t)i1 * 2654435761u;
        const uint32_t B1 = ((uint32_t)i1 + 1u) * 2654435761u;
        const uint32_t C0 = (uint32_t)i2 * 805459861u;
        const uint32_t C1 = ((uint32_t)i2 + 1u) * 805459861u;

        const uint32_t h0 = A1 ^ B1 ^ C1;                                              // j=0: rank>=0 all
        const uint32_t h1 = (r0 >= 1 ? A1 : A0) ^ (r1 >= 1 ? B1 : B0) ^ (r2 >= 1 ? C1 : C0);
        const uint32_t h2 = (r0 >= 2 ? A1 : A0) ^ (r1 >= 2 ? B1 : B0) ^ (r2 >= 2 ? C1 : C0);
        const uint32_t h3 = A0 ^ B0 ^ C0;                                              // j=3: none

        const float2 e0 = *reinterpret_cast<const float2*>(emb + 2u * ((h0 & mask) + prev));
        const float2 e1 = *reinterpret_cast<const float2*>(emb + 2u * ((h1 & mask) + prev));
        const float2 e2 = *reinterpret_cast<const float2*>(emb + 2u * ((h2 & mask) + prev));
        const float2 e3 = *reinterpret_cast<const float2*>(emb + 2u * ((h3 & mask) + prev));

        acc[2 * lvl + 0] = w0 * e0.x + w1 * e1.x + w2 * e2.x + w3 * e3.x;
        acc[2 * lvl + 1] = w0 * e0.y + w1 * e1.y + w2 * e2.y + w3 * e3.y;
    }

    f32x4* o = reinterpret_cast<f32x4*>(out) + (size_t)b * 8u;
#pragma unroll
    for (int q = 0; q < 8; ++q) {
        f32x4 v;
        v.x = acc[4 * q + 0];
        v.y = acc[4 * q + 1];
        v.z = acc[4 * q + 2];
        v.w = acc[4 * q + 3];
        __builtin_nontemporal_store(v, o + q);
    }
}

extern "C" void kernel_launch(void* const* d_in, const int* in_sizes, int n_in,
                              void* d_out, int out_size, void* d_ws, size_t ws_size,
                              hipStream_t stream) {
    const float* in  = (const float*)d_in[0];
    const float* emb = (const float*)d_in[1];
    float* out = (float*)d_out;

    dim3 grid(kBatch / 256u);
    dim3 block(256u);
    hipLaunchKernelGGL(pyramid_fwd, grid, block, 0, stream, in, emb, out);
}

// Round 4
// 1267.687 us; speedup vs baseline: 1.1473x; 1.1473x over previous
//
#include <hip/hip_runtime.h>
#include <stdint.h>

// PyramidGrid (instant-NGP hash grid, simplex/tetrahedral interp) forward.
// BATCH = 2^21 points, 16 levels, LEVEL_DIM=2, table rows = 7,114,752.
//
// R3: MLP restructure. R2 post-mortem refuted the L3-thrash theory (NT stores
// left FETCH_SIZE unchanged and inflated WRITE_SIZE 2.4x -> reverted). New
// theory: latency-bound at VGPR=36 (only ~4 gathers in flight). Now: 2 groups
// of 8 levels; per group compute all indices, issue all 32 independent float2
// gathers before any consume (static unrolled arrays -> registers), then
// combine + 64B/lane store. __launch_bounds__(256,4) -> 128 VGPR budget.

constexpr uint32_t kBatch = 1u << 21;

typedef float f32x4 __attribute__((ext_vector_type(4)));

__global__ __launch_bounds__(256, 4) void pyramid_fwd(
    const float* __restrict__ in,    // [B,3]
    const float* __restrict__ emb,   // [7114752,2]
    float* __restrict__ out)         // [B,32]
{
    const uint32_t b = blockIdx.x * 256u + threadIdx.x;

    const float x0 = in[3u * b + 0u];
    const float x1 = in[3u * b + 1u];
    const float x2 = in[3u * b + 2u];

    // cumulative row offsets (prev) and hash masks per level
    constexpr uint32_t PREV[16] = {
        0u, 4096u, 36864u, 299008u, 823296u, 1347584u, 1871872u, 2396160u,
        2920448u, 3444736u, 3969024u, 4493312u, 5017600u, 5541888u, 6066176u, 6590464u};
    constexpr uint32_t MASK[16] = {
        4095u, 32767u, 262143u, 524287u, 524287u, 524287u, 524287u, 524287u,
        524287u, 524287u, 524287u, 524287u, 524287u, 524287u, 524287u, 524287u};

#pragma unroll
    for (int g = 0; g < 2; ++g) {
        float2 e[8][4];                 // 32 gather results (64 VGPRs), static-indexed
        float sa[8], sb[8], sc[8];      // sorted fracs per level

        // Phase A: compute indices and ISSUE all 32 loads, no consumes yet.
#pragma unroll
        for (int k = 0; k < 8; ++k) {
            const int lvl = g * 8 + k;
            const float res = (float)(16 << lvl);
            const uint32_t mask = MASK[lvl];
            const uint32_t prev = PREV[lvl];

            const float fx0 = x0 * res;
            const float fx1 = x1 * res;
            const float fx2 = x2 * res;
            const int i0 = (int)fx0;          // trunc == floor (x >= 0)
            const int i1 = (int)fx1;
            const int i2 = (int)fx2;
            const float f0 = fx0 - (float)i0; // exact fp32, matches reference
            const float f1 = fx1 - (float)i1;
            const float f2 = fx2 - (float)i2;

            // stable ascending ranks (== inv_inds of stable argsort)
            const int r0 = (int)(f1 < f0) + (int)(f2 < f0);
            const int r1 = (int)(f0 < f1) + (int)(f2 < f1) + (int)(f0 == f1);
            const int r2 = (int)(f0 < f2) + (int)(f1 < f2) + (int)(f0 == f2) + (int)(f1 == f2);

            // sorted frac values (exact selections)
            sa[k] = fminf(fminf(f0, f1), f2);
            sc[k] = fmaxf(fmaxf(f0, f1), f2);
            sb[k] = __builtin_amdgcn_fmed3f(f0, f1, f2);

            // hash components (uint32 wrap multiply; PRIMES = {1, 2654435761, 805459861})
            const uint32_t A0 = (uint32_t)i0;
            const uint32_t A1 = A0 + 1u;
            const uint32_t B0 = (uint32_t)i1 * 2654435761u;
            const uint32_t B1 = ((uint32_t)i1 + 1u) * 2654435761u;
            const uint32_t C0 = (uint32_t)i2 * 805459861u;
            const uint32_t C1 = ((uint32_t)i2 + 1u) * 805459861u;

            const uint32_t h0 = A1 ^ B1 ^ C1;                                        // all +1
            const uint32_t h1 = (r0 >= 1 ? A1 : A0) ^ (r1 >= 1 ? B1 : B0) ^ (r2 >= 1 ? C1 : C0);
            const uint32_t h2 = (r0 >= 2 ? A1 : A0) ^ (r1 >= 2 ? B1 : B0) ^ (r2 >= 2 ? C1 : C0);
            const uint32_t h3 = A0 ^ B0 ^ C0;                                        // base

            e[k][0] = *reinterpret_cast<const float2*>(emb + 2u * ((h0 & mask) + prev));
            e[k][1] = *reinterpret_cast<const float2*>(emb + 2u * ((h1 & mask) + prev));
            e[k][2] = *reinterpret_cast<const float2*>(emb + 2u * ((h2 & mask) + prev));
            e[k][3] = *reinterpret_cast<const float2*>(emb + 2u * ((h3 & mask) + prev));
        }

        // Phase B: combine (drains vmcnt progressively, oldest first).
        float o8[16];
#pragma unroll
        for (int k = 0; k < 8; ++k) {
            const float w0 = sa[k];
            const float w1 = sb[k] - sa[k];
            const float w2 = sc[k] - sb[k];
            const float w3 = 1.0f - sc[k];
            o8[2 * k + 0] = w0 * e[k][0].x + w1 * e[k][1].x + w2 * e[k][2].x + w3 * e[k][3].x;
            o8[2 * k + 1] = w0 * e[k][0].y + w1 * e[k][1].y + w2 * e[k][2].y + w3 * e[k][3].y;
        }

        // Phase C: 64B contiguous store per lane (one full line per lane).
        f32x4* o = reinterpret_cast<f32x4*>(out + (size_t)b * 32u + (size_t)g * 16u);
#pragma unroll
        for (int q = 0; q < 4; ++q) {
            f32x4 v;
            v.x = o8[4 * q + 0];
            v.y = o8[4 * q + 1];
            v.z = o8[4 * q + 2];
            v.w = o8[4 * q + 3];
            o[q] = v;
        }
    }
}

extern "C" void kernel_launch(void* const* d_in, const int* in_sizes, int n_in,
                              void* d_out, int out_size, void* d_ws, size_t ws_size,
                              hipStream_t stream) {
    const float* in  = (const float*)d_in[0];
    const float* emb = (const float*)d_in[1];
    float* out = (float*)d_out;

    dim3 grid(kBatch / 256u);
    dim3 block(256u);
    hipLaunchKernelGGL(pyramid_fwd, grid, block, 0, stream, in, emb, out);
}

// Round 5
// 1258.117 us; speedup vs baseline: 1.1561x; 1.0076x over previous
//
#include <hip/hip_runtime.h>
#include <stdint.h>

// PyramidGrid (instant-NGP hash grid, simplex/tetrahedral interp) forward.
// BATCH = 2^21 points, 16 levels, LEVEL_DIM=2, table rows = 7,114,752.
//
// R5: R4's MLP restructure never ran — VGPR stayed 36 because the compiler
// sank loads back next to consumes. Force it with sched_barrier(0) between
// phase A (issue 32 independent gathers) and phase B (consume): loads cannot
// cross the fence, so 64 result floats stay live -> ~32 loads in flight/wave.

constexpr uint32_t kBatch = 1u << 21;

typedef float f32x4 __attribute__((ext_vector_type(4)));

__global__ __launch_bounds__(256, 4) void pyramid_fwd(
    const float* __restrict__ in,    // [B,3]
    const float* __restrict__ emb,   // [7114752,2]
    float* __restrict__ out)         // [B,32]
{
    const uint32_t b = blockIdx.x * 256u + threadIdx.x;

    const float x0 = in[3u * b + 0u];
    const float x1 = in[3u * b + 1u];
    const float x2 = in[3u * b + 2u];

    // cumulative row offsets (prev) and hash masks per level
    constexpr uint32_t PREV[16] = {
        0u, 4096u, 36864u, 299008u, 823296u, 1347584u, 1871872u, 2396160u,
        2920448u, 3444736u, 3969024u, 4493312u, 5017600u, 5541888u, 6066176u, 6590464u};
    constexpr uint32_t MASK[16] = {
        4095u, 32767u, 262143u, 524287u, 524287u, 524287u, 524287u, 524287u,
        524287u, 524287u, 524287u, 524287u, 524287u, 524287u, 524287u, 524287u};

#pragma unroll
    for (int g = 0; g < 2; ++g) {
        float2 e[8][4];                 // 32 gather results (64 VGPRs), static-indexed
        float sa[8], sb[8], sc[8];      // sorted fracs per level

        // Phase A: compute indices and ISSUE all 32 loads, no consumes yet.
#pragma unroll
        for (int k = 0; k < 8; ++k) {
            const int lvl = g * 8 + k;
            const float res = (float)(16 << lvl);
            const uint32_t mask = MASK[lvl];
            const uint32_t prev = PREV[lvl];

            const float fx0 = x0 * res;
            const float fx1 = x1 * res;
            const float fx2 = x2 * res;
            const int i0 = (int)fx0;          // trunc == floor (x >= 0)
            const int i1 = (int)fx1;
            const int i2 = (int)fx2;
            const float f0 = fx0 - (float)i0; // exact fp32, matches reference
            const float f1 = fx1 - (float)i1;
            const float f2 = fx2 - (float)i2;

            // stable ascending ranks (== inv_inds of stable argsort)
            const int r0 = (int)(f1 < f0) + (int)(f2 < f0);
            const int r1 = (int)(f0 < f1) + (int)(f2 < f1) + (int)(f0 == f1);
            const int r2 = (int)(f0 < f2) + (int)(f1 < f2) + (int)(f0 == f2) + (int)(f1 == f2);

            // sorted frac values (exact selections)
            sa[k] = fminf(fminf(f0, f1), f2);
            sc[k] = fmaxf(fmaxf(f0, f1), f2);
            sb[k] = __builtin_amdgcn_fmed3f(f0, f1, f2);

            // hash components (uint32 wrap multiply; PRIMES = {1, 2654435761, 805459861})
            const uint32_t A0 = (uint32_t)i0;
            const uint32_t A1 = A0 + 1u;
            const uint32_t B0 = (uint32_t)i1 * 2654435761u;
            const uint32_t B1 = ((uint32_t)i1 + 1u) * 2654435761u;
            const uint32_t C0 = (uint32_t)i2 * 805459861u;
            const uint32_t C1 = ((uint32_t)i2 + 1u) * 805459861u;

            const uint32_t h0 = A1 ^ B1 ^ C1;                                        // all +1
            const uint32_t h1 = (r0 >= 1 ? A1 : A0) ^ (r1 >= 1 ? B1 : B0) ^ (r2 >= 1 ? C1 : C0);
            const uint32_t h2 = (r0 >= 2 ? A1 : A0) ^ (r1 >= 2 ? B1 : B0) ^ (r2 >= 2 ? C1 : C0);
            const uint32_t h3 = A0 ^ B0 ^ C0;                                        // base

            e[k][0] = *reinterpret_cast<const float2*>(emb + 2u * ((h0 & mask) + prev));
            e[k][1] = *reinterpret_cast<const float2*>(emb + 2u * ((h1 & mask) + prev));
            e[k][2] = *reinterpret_cast<const float2*>(emb + 2u * ((h2 & mask) + prev));
            e[k][3] = *reinterpret_cast<const float2*>(emb + 2u * ((h3 & mask) + prev));
        }

        // Hard scheduling fence: no instruction (in particular no load) may
        // cross. Forces all 32 gathers above to be issued before any consume.
        __builtin_amdgcn_sched_barrier(0);

        // Phase B: combine (drains vmcnt progressively, oldest first).
        float o8[16];
#pragma unroll
        for (int k = 0; k < 8; ++k) {
            const float w0 = sa[k];
            const float w1 = sb[k] - sa[k];
            const float w2 = sc[k] - sb[k];
            const float w3 = 1.0f - sc[k];
            o8[2 * k + 0] = w0 * e[k][0].x + w1 * e[k][1].x + w2 * e[k][2].x + w3 * e[k][3].x;
            o8[2 * k + 1] = w0 * e[k][0].y + w1 * e[k][1].y + w2 * e[k][2].y + w3 * e[k][3].y;
        }

        // Phase C: 64B contiguous store per lane (one full line per lane).
        f32x4* o = reinterpret_cast<f32x4*>(out + (size_t)b * 32u + (size_t)g * 16u);
#pragma unroll
        for (int q = 0; q < 4; ++q) {
            f32x4 v;
            v.x = o8[4 * q + 0];
            v.y = o8[4 * q + 1];
            v.z = o8[4 * q + 2];
            v.w = o8[4 * q + 3];
            o[q] = v;
        }
    }
}

extern "C" void kernel_launch(void* const* d_in, const int* in_sizes, int n_in,
                              void* d_out, int out_size, void* d_ws, size_t ws_size,
                              hipStream_t stream) {
    const float* in  = (const float*)d_in[0];
    const float* emb = (const float*)d_in[1];
    float* out = (float*)d_out;

    dim3 grid(kBatch / 256u);
    dim3 block(256u);
    hipLaunchKernelGGL(pyramid_fwd, grid, block, 0, stream, in, emb, out);
}